// Round 1
// baseline (1021.720 us; speedup 1.0000x reference)
//
#include <hip/hip_runtime.h>
#include <math.h>

#define NROWS 65536
#define KEMB  2048
#define DIM   64
#define DECAYF 0.99f
#define OMDF   0.01f
#define EPSF   1e-5f

// ---- ws layout (units of 4 bytes) ----
#define WS_DW    0         // 131072 floats (dw accumulator, zeroed each call)
#define WS_CNT   131072    // 2048 uints   (counts, zeroed each call)
#define WS_LOSS  133120    // 1 float      (loss accumulator, zeroed each call)
#define WS_ESQ   133632    // 2048 floats  (e_sq)
#define WS_SCALE 135680    // 2048 floats  (0.01/cs', K3->K4)
#define WS_IDX   137728    // 65536 ints   (argmin indices)

// ---- out layout (floats) ----
#define OUT_Q    0
#define OUT_ENC  4194304          // 65536*64
#define OUT_LOSS 138412032        // + 65536*2048
#define OUT_PERP 138412033
#define OUT_NE   138412034        // new_embedding (NOT 16B aligned -> float2 stores)
#define OUT_NCS  138543106        // + 2048*64

typedef float f32x4 __attribute__((ext_vector_type(4)));

// K0: zero accumulators, precompute e_sq
__global__ __launch_bounds__(256) void k0_prep(const float* __restrict__ E,
                                               float* __restrict__ ws) {
    int g = blockIdx.x * 256 + threadIdx.x;  // 64 blocks -> 16384 threads
    float4 z = make_float4(0.f, 0.f, 0.f, 0.f);
    float4* wsf4 = (float4*)ws;
    // zero [0, 133120) floats = 33280 float4
    for (int i = g; i < 33280; i += 16384) wsf4[i] = z;
    if (g == 0) ws[WS_LOSS] = 0.f;
    if (g < KEMB) {
        const float4* e4 = (const float4*)(E + (size_t)g * DIM);
        float s0 = 0.f, s1 = 0.f, s2 = 0.f, s3 = 0.f;
#pragma unroll
        for (int j = 0; j < 16; j++) {
            float4 v = e4[j];
            s0 = fmaf(v.x, v.x, s0); s1 = fmaf(v.y, v.y, s1);
            s2 = fmaf(v.z, v.z, s2); s3 = fmaf(v.w, v.w, s3);
        }
        ws[WS_ESQ + g] = (s0 + s1) + (s2 + s3);
    }
}

// K1: fused argmin + quantized + loss + counts + dw atomics + 512MB zero-fill
// 512 blocks x 256 threads. Block handles 128 rows; threads t<128 do k<1024,
// t>=128 do k>=1024 for the same rows (k-split -> 2 waves/SIMD for latency hiding).
__global__ __launch_bounds__(256, 2) void k1_main(const float* __restrict__ x,
                                                  const float* __restrict__ E,
                                                  float* __restrict__ ws,
                                                  float* __restrict__ out) {
    __shared__ float se[2][128 * DIM];  // 64 KB exactly

    const int t = threadIdx.x;
    const int b = blockIdx.x;
    const int lane = t & 127;
    const int h = t >> 7;            // k-half
    const int row = b * 128 + lane;
    const float* __restrict__ esq = ws + WS_ESQ;
    f32x4* __restrict__ encz = (f32x4*)(out + OUT_ENC);
    const int g = b * 256 + t;       // zero-fill id in [0, 131072)

    // load my row into registers
    float xr[64];
    {
        const float4* x4 = (const float4*)(x + (size_t)row * DIM);
#pragma unroll
        for (int j = 0; j < 16; j++) ((float4*)xr)[j] = x4[j];
    }
    float xs0 = 0.f, xs1 = 0.f, xs2 = 0.f, xs3 = 0.f;
#pragma unroll
    for (int j = 0; j < 16; j++) {
        xs0 = fmaf(xr[4 * j + 0], xr[4 * j + 0], xs0);
        xs1 = fmaf(xr[4 * j + 1], xr[4 * j + 1], xs1);
        xs2 = fmaf(xr[4 * j + 2], xr[4 * j + 2], xs2);
        xs3 = fmaf(xr[4 * j + 3], xr[4 * j + 3], xs3);
    }
    const float x_sq = (xs0 + xs1) + (xs2 + xs3);

    float best = 3.4e38f;
    int bidx = 0;

    for (int i = 0; i < 8; i++) {
        __syncthreads();  // protect LDS reuse
        {   // stage tile i -> se[0], tile 8+i -> se[1]  (2048 float4 per buffer)
            const float4* src0 = (const float4*)(E + (size_t)i * 128 * DIM);
            const float4* src1 = (const float4*)(E + (size_t)(8 + i) * 128 * DIM);
            float4* d0 = (float4*)se[0];
            float4* d1 = (float4*)se[1];
#pragma unroll
            for (int j = 0; j < 8; j++) d0[t + j * 256] = src0[t + j * 256];
#pragma unroll
            for (int j = 0; j < 8; j++) d1[t + j * 256] = src1[t + j * 256];
        }
        __syncthreads();

        // zero-fill slice of encodings (overlaps with compute; drains at next barrier)
        {
            f32x4 z = (f32x4)(0.f);
            f32x4* p = encz + (size_t)(i * 32) * 131072 + g;
#pragma unroll 4
            for (int j = 0; j < 32; j++) {
                __builtin_nontemporal_store(z, p);
                p += 131072;
            }
        }

        const float* eb = se[h];
        const int kbase = (h * 8 + i) * 128;
        for (int k = 0; k < 128; k++) {
            const float4* e4 = (const float4*)(eb + k * DIM);
            float s0 = 0.f, s1 = 0.f, s2 = 0.f, s3 = 0.f;
#pragma unroll
            for (int j = 0; j < 16; j++) {
                float4 ev = e4[j];
                s0 = fmaf(xr[4 * j + 0], ev.x, s0);
                s1 = fmaf(xr[4 * j + 1], ev.y, s1);
                s2 = fmaf(xr[4 * j + 2], ev.z, s2);
                s3 = fmaf(xr[4 * j + 3], ev.w, s3);
            }
            float cr = (s0 + s1) + (s2 + s3);
            // match reference rounding: (x_sq - 2*cross) + e_sq
            float dist = (x_sq - (cr + cr)) + esq[kbase + k];
            if (dist < best) { best = dist; bidx = kbase + k; }
        }
    }

    // combine the two k-halves (half A has lower k -> wins ties via strict <)
    __syncthreads();
    float* sf = se[0];
    int* si = (int*)(se[0]) + 256;
    sf[t] = best;
    si[t] = bidx;
    __syncthreads();
    if (t < 128) {
        float bB = sf[t + 128];
        int iB = si[t + 128];
        if (bB < best) { best = bB; bidx = iB; }

        int* idxp = ((int*)ws) + WS_IDX;
        idxp[row] = bidx;

        // gather embedding, write quantized, accumulate loss
        const float4* ebb = (const float4*)(E + (size_t)bidx * DIM);
        float4* qo = (float4*)(out + OUT_Q + (size_t)row * DIM);
        float l0 = 0.f, l1 = 0.f, l2 = 0.f, l3 = 0.f;
#pragma unroll
        for (int j = 0; j < 16; j++) {
            float4 ev = ebb[j];
            qo[j] = ev;
            float d0 = ev.x - xr[4 * j + 0];
            float d1 = ev.y - xr[4 * j + 1];
            float d2 = ev.z - xr[4 * j + 2];
            float d3 = ev.w - xr[4 * j + 3];
            l0 = fmaf(d0, d0, l0); l1 = fmaf(d1, d1, l1);
            l2 = fmaf(d2, d2, l2); l3 = fmaf(d3, d3, l3);
        }
        float lsum = (l0 + l1) + (l2 + l3);
#pragma unroll
        for (int o = 32; o; o >>= 1) lsum += __shfl_down(lsum, o, 64);
        if ((t & 63) == 0) unsafeAtomicAdd(ws + WS_LOSS, lsum);

        atomicAdd(((unsigned int*)ws) + WS_CNT + bidx, 1u);

        float* dw = ws + WS_DW + (size_t)bidx * DIM;
#pragma unroll
        for (int j = 0; j < 64; j++) unsafeAtomicAdd(dw + j, xr[j]);
    }
}

// K2: scatter the one-hot 1.0s
__global__ __launch_bounds__(256) void k2_ones(const int* __restrict__ idxp,
                                               float* __restrict__ out) {
    int n = blockIdx.x * 256 + threadIdx.x;  // 256 blocks
    out[OUT_ENC + (size_t)n * KEMB + idxp[n]] = 1.0f;
}

// K3: cluster stats, loss, perplexity, scale for K4. One block of 256.
__global__ __launch_bounds__(256) void k3_stats(const float* __restrict__ cs_in,
                                                float* __restrict__ ws,
                                                float* __restrict__ out) {
    __shared__ float sred[8];
    __shared__ float s_n;
    int t = threadIdx.x;
    const unsigned int* cnt = ((const unsigned int*)ws) + WS_CNT;
    float* ncs_out = out + OUT_NCS;

    float ln = 0.f, lent = 0.f;
    float ncs_v[8];
#pragma unroll
    for (int j = 0; j < 8; j++) {
        int k = t + j * 256;
        float c = (float)cnt[k];
        float ncs = DECAYF * cs_in[k] + OMDF * c;
        ncs_out[k] = ncs;
        ncs_v[j] = ncs;
        ln += ncs;
        float p = c * (1.0f / 65536.0f);
        lent = fmaf(p, logf(p + 1e-10f), lent);
    }
#pragma unroll
    for (int o = 32; o; o >>= 1) {
        ln += __shfl_down(ln, o, 64);
        lent += __shfl_down(lent, o, 64);
    }
    if ((t & 63) == 0) { sred[t >> 6] = ln; sred[4 + (t >> 6)] = lent; }
    __syncthreads();
    if (t == 0) {
        float n = (sred[0] + sred[1]) + (sred[2] + sred[3]);
        float ent = (sred[4] + sred[5]) + (sred[6] + sred[7]);
        s_n = n;
        out[OUT_LOSS] = ws[WS_LOSS] * (1.0f / 4194304.0f);
        out[OUT_PERP] = expf(-ent);
    }
    __syncthreads();
    float n = s_n;
    float denom = n + (float)KEMB * EPSF;
#pragma unroll
    for (int j = 0; j < 8; j++) {
        int k = t + j * 256;
        float cs = (ncs_v[j] + EPSF) / denom * n;
        ws[WS_SCALE + k] = OMDF / cs;
    }
}

// K4: new_embedding = decay*E + dw * (0.01/cs).  Output base not 16B aligned -> float2 stores.
__global__ __launch_bounds__(256) void k4_embed(const float* __restrict__ E,
                                                const float* __restrict__ ws,
                                                float* __restrict__ out) {
    int gq = blockIdx.x * 256 + threadIdx.x;  // 128 blocks -> 32768 float4-granules
    const float4* E4 = (const float4*)E;
    const float4* dw4 = (const float4*)(ws + WS_DW);
    float2* o2 = (float2*)(out + OUT_NE);
    int k = gq >> 4;
    float sc = ws[WS_SCALE + k];
    float4 e = E4[gq];
    float4 d = dw4[gq];
    float2 r0, r1;
    r0.x = fmaf(d.x, sc, DECAYF * e.x);
    r0.y = fmaf(d.y, sc, DECAYF * e.y);
    r1.x = fmaf(d.z, sc, DECAYF * e.z);
    r1.y = fmaf(d.w, sc, DECAYF * e.w);
    o2[2 * gq + 0] = r0;
    o2[2 * gq + 1] = r1;
}

extern "C" void kernel_launch(void* const* d_in, const int* in_sizes, int n_in,
                              void* d_out, int out_size, void* d_ws, size_t ws_size,
                              hipStream_t stream) {
    const float* x = (const float*)d_in[0];
    const float* E = (const float*)d_in[1];
    const float* cs = (const float*)d_in[2];
    float* out = (float*)d_out;
    float* ws = (float*)d_ws;

    hipLaunchKernelGGL(k0_prep, dim3(64), dim3(256), 0, stream, E, ws);
    hipLaunchKernelGGL(k1_main, dim3(512), dim3(256), 0, stream, x, E, ws, out);
    hipLaunchKernelGGL(k2_ones, dim3(256), dim3(256), 0, stream,
                       ((const int*)ws) + WS_IDX, out);
    hipLaunchKernelGGL(k3_stats, dim3(1), dim3(256), 0, stream, cs, ws, out);
    hipLaunchKernelGGL(k4_embed, dim3(128), dim3(256), 0, stream, E, ws, out);
}